// Round 1
// baseline (413.993 us; speedup 1.0000x reference)
//
#include <hip/hip_runtime.h>
#include <hip/hip_bf16.h>

// Problem constants (fixed by harness setup_inputs).
#define S_LEN  2048
#define DMODEL 1024
#define NHEADS 16
#define DHEAD  64
#define TOKENS 4096   // B*S
#define BHN    32     // B*H

typedef __attribute__((ext_vector_type(8))) short bf16x8;
typedef __attribute__((ext_vector_type(4))) float f32x4;

__device__ __forceinline__ unsigned short f2bf(float x) {
    union { float f; unsigned u; } v; v.f = x;
    unsigned r = v.u + 0x7FFFu + ((v.u >> 16) & 1u);   // RNE
    return (unsigned short)(r >> 16);
}
__device__ __forceinline__ float bf2f(unsigned short b) {
    union { unsigned u; float f; } v; v.u = ((unsigned)b) << 16;
    return v.f;
}

// ---------------------------------------------------------------------------
// Kernel 1: fused 4-way projection GEMM.  out = X @ W^T + b, written as bf16
// in [B,H,S,DHEAD] layout.  M=4096, N=1024, K=1024.  BM=BN=128, BK=32.
// blockIdx.z selects {q,k,v,p}.
// ---------------------------------------------------------------------------
__global__ __launch_bounds__(256) void proj_gemm(
    const float* __restrict__ x0, const float* __restrict__ x1,
    const float* __restrict__ x2, const float* __restrict__ x3,
    const float* __restrict__ w0, const float* __restrict__ w1,
    const float* __restrict__ w2, const float* __restrict__ w3,
    const float* __restrict__ b0, const float* __restrict__ b1,
    const float* __restrict__ b2, const float* __restrict__ b3,
    unsigned short* __restrict__ o0, unsigned short* __restrict__ o1,
    unsigned short* __restrict__ o2, unsigned short* __restrict__ o3)
{
    const int z = blockIdx.z;
    const float* X  = (z == 0) ? x0 : (z == 1) ? x1 : (z == 2) ? x2 : x3;
    const float* W  = (z == 0) ? w0 : (z == 1) ? w1 : (z == 2) ? w2 : w3;
    const float* Bv = (z == 0) ? b0 : (z == 1) ? b1 : (z == 2) ? b2 : b3;
    unsigned short* O = (z == 0) ? o0 : (z == 1) ? o1 : (z == 2) ? o2 : o3;

    __shared__ __align__(16) unsigned short At[128 * 40]; // stride 40 bf16 (80B, 16B-aligned rows)
    __shared__ __align__(16) unsigned short Bt[128 * 40];

    const int tid  = threadIdx.x;
    const int lane = tid & 63;
    const int w    = tid >> 6;
    const int wr   = w & 1, wc = w >> 1;
    const int m0   = blockIdx.x * 128;
    const int n0   = blockIdx.y * 128;
    const int l16  = lane & 15, lq = lane >> 4;

    f32x4 acc[4][4];
    #pragma unroll
    for (int i = 0; i < 4; i++)
        #pragma unroll
        for (int j = 0; j < 4; j++) acc[i][j] = (f32x4){0.f, 0.f, 0.f, 0.f};

    for (int k0 = 0; k0 < DMODEL; k0 += 32) {
        __syncthreads();
        #pragma unroll
        for (int i = 0; i < 4; i++) {
            int e = tid + i * 256;
            int row = e >> 3, cg = e & 7;
            float4 va = *(const float4*)&X[(long)(m0 + row) * DMODEL + k0 + cg * 4];
            ushort4 ua; ua.x = f2bf(va.x); ua.y = f2bf(va.y); ua.z = f2bf(va.z); ua.w = f2bf(va.w);
            *(ushort4*)&At[row * 40 + cg * 4] = ua;
            float4 vb = *(const float4*)&W[(long)(n0 + row) * DMODEL + k0 + cg * 4];
            ushort4 ub; ub.x = f2bf(vb.x); ub.y = f2bf(vb.y); ub.z = f2bf(vb.z); ub.w = f2bf(vb.w);
            *(ushort4*)&Bt[row * 40 + cg * 4] = ub;
        }
        __syncthreads();
        bf16x8 af[4], bfr[4];
        #pragma unroll
        for (int f = 0; f < 4; f++) {
            af[f]  = *(const bf16x8*)&At[(64 * wr + 16 * f + l16) * 40 + 8 * lq];
            bfr[f] = *(const bf16x8*)&Bt[(64 * wc + 16 * f + l16) * 40 + 8 * lq];
        }
        #pragma unroll
        for (int i = 0; i < 4; i++)
            #pragma unroll
            for (int j = 0; j < 4; j++)
                acc[i][j] = __builtin_amdgcn_mfma_f32_16x16x32_bf16(af[i], bfr[j], acc[i][j], 0, 0, 0);
    }

    #pragma unroll
    for (int j = 0; j < 4; j++) {
        int n_g = n0 + 64 * wc + 16 * j + l16;
        float bias = Bv[n_g];
        int h = n_g >> 6, dh = n_g & 63;
        #pragma unroll
        for (int i = 0; i < 4; i++) {
            #pragma unroll
            for (int r = 0; r < 4; r++) {
                int m_g = m0 + 64 * wr + 16 * i + 4 * lq + r;
                int b = m_g >> 11, s = m_g & (S_LEN - 1);
                O[(long)(((b * NHEADS + h) * S_LEN) + s) * DHEAD + dh] = f2bf(acc[i][j][r] + bias);
            }
        }
    }
}

// ---------------------------------------------------------------------------
// Kernel 2: fused relative-position flash attention.
// Grid: (q-tile 0..31, bh 0..31).  4 waves, QB=64 rows/block, KB=64 cols/tile.
// shifted pos score: T[r,t] = q[q0+rowoff+r] . P2[mbase+t]  (64 x 128 tile),
// read at T[qi+s-rowoff][ci-qi+63].
// ---------------------------------------------------------------------------
__global__ __launch_bounds__(256) void rel_attn(
    const unsigned short* __restrict__ Q,   // [BH][S][64] bf16
    const unsigned short* __restrict__ K,
    const unsigned short* __restrict__ V,
    const unsigned short* __restrict__ P,
    unsigned short* __restrict__ CTX)       // [B][S][H][64] bf16
{
    __shared__ __align__(16) unsigned short Qx[66 * 72];   // rows q0..q0+64 (+1 spare)
    __shared__ __align__(16) unsigned short Kt[64 * 72];
    __shared__ __align__(16) unsigned short Vt[64 * 72];   // transposed: [dh][ci]
    __shared__ __align__(16) unsigned short Xb[128 * 72];  // alias: P2win[128][72] / T[64][132] / Pattn[64][72]

    const int tid  = threadIdx.x;
    const int lane = tid & 63;
    const int w    = tid >> 6;
    const int l16  = lane & 15, lq = lane >> 4;
    const int q0   = blockIdx.x * 64;
    const int bh   = blockIdx.y;
    const long base = (long)bh * S_LEN * DHEAD;

    // stage Qx rows 0..64 (zero-fill OOB)
    #pragma unroll
    for (int i = 0; i < 3; i++) {
        int e = tid + i * 256;
        if (e < 65 * 8) {
            int row = e >> 3, sg = e & 7;
            int gq = q0 + row;
            float4 val = (float4){0.f, 0.f, 0.f, 0.f};
            if (gq < S_LEN) val = *(const float4*)&Q[base + (long)gq * DHEAD + sg * 8];
            *(float4*)&Qx[row * 72 + sg * 8] = val;
        }
    }
    __syncthreads();

    // hoist Q fragments: content (row offset 0) and both T row-offsets
    bf16x8 aq[2], at0[2], at1[2];
    #pragma unroll
    for (int kk = 0; kk < 2; kk++) {
        aq[kk]  = *(const bf16x8*)&Qx[(16 * w + l16) * 72 + kk * 32 + 8 * lq];
        at0[kk] = aq[kk];
        at1[kk] = *(const bf16x8*)&Qx[(16 * w + 1 + l16) * 72 + kk * 32 + 8 * lq];
    }

    float mrow[4], lrow[4];
    f32x4 oacc[4];
    #pragma unroll
    for (int r = 0; r < 4; r++) { mrow[r] = -1e30f; lrow[r] = 0.f; }
    #pragma unroll
    for (int f = 0; f < 4; f++) oacc[f] = (f32x4){0.f, 0.f, 0.f, 0.f};

    for (int ct = 0; ct < S_LEN / 64; ++ct) {
        const int c0 = ct * 64;
        const int mbase = c0 - q0 + 1984;   // c0 - q0 + (S-1) - (QB-1)
        __syncthreads();
        // ---- stage K tile ----
        #pragma unroll
        for (int i = 0; i < 2; i++) {
            int e = tid + i * 256;
            int row = e >> 3, sg = e & 7;
            *(float4*)&Kt[row * 72 + sg * 8] =
                *(const float4*)&K[base + (long)(c0 + row) * DHEAD + sg * 8];
        }
        // ---- stage V tile transposed ----
        #pragma unroll
        for (int i = 0; i < 2; i++) {
            int e = tid + i * 256;
            int ci = e & 63, sg = (e >> 6) & 7;
            float4 vv = *(const float4*)&V[base + (long)(c0 + ci) * DHEAD + sg * 8];
            const unsigned short* u = (const unsigned short*)&vv;
            #pragma unroll
            for (int jj = 0; jj < 8; jj++) Vt[(sg * 8 + jj) * 72 + ci] = u[jj];
        }
        // ---- stage P2 window (128 rows) ----
        #pragma unroll
        for (int i = 0; i < 4; i++) {
            int e = tid + i * 256;
            int row = e >> 3, sg = e & 7;
            int m = mbase + row;
            float4 val = (float4){0.f, 0.f, 0.f, 0.f};
            int pr = (m >= 2049) ? (m - 2049) : m;
            if (m >= 0 && m != 2048 && pr < S_LEN)
                val = *(const float4*)&P[base + (long)pr * DHEAD + sg * 8];
            *(float4*)&Xb[row * 72 + sg * 8] = val;
        }
        __syncthreads();

        // ---- content QK^T ----
        f32x4 cacc[4];
        #pragma unroll
        for (int f = 0; f < 4; f++) cacc[f] = (f32x4){0.f, 0.f, 0.f, 0.f};
        #pragma unroll
        for (int fc = 0; fc < 4; ++fc)
            #pragma unroll
            for (int kk = 0; kk < 2; ++kk) {
                bf16x8 b = *(const bf16x8*)&Kt[(16 * fc + l16) * 72 + kk * 32 + 8 * lq];
                cacc[fc] = __builtin_amdgcn_mfma_f32_16x16x32_bf16(aq[kk], b, cacc[fc], 0, 0, 0);
            }

        // ---- T = Qshift . P2win  (wave w owns T rows 16w..16w+15, cols 0..127) ----
        const int rowoff = (c0 > q0) ? 1 : 0;
        f32x4 tacc[8];
        #pragma unroll
        for (int cg = 0; cg < 8; cg++) tacc[cg] = (f32x4){0.f, 0.f, 0.f, 0.f};
        #pragma unroll
        for (int cg = 0; cg < 8; ++cg)
            #pragma unroll
            for (int kk = 0; kk < 2; ++kk) {
                bf16x8 b = *(const bf16x8*)&Xb[(16 * cg + l16) * 72 + kk * 32 + 8 * lq];
                bf16x8 a = rowoff ? at1[kk] : at0[kk];
                tacc[cg] = __builtin_amdgcn_mfma_f32_16x16x32_bf16(a, b, tacc[cg], 0, 0, 0);
            }
        __syncthreads();   // all P2win reads complete -> safe to overwrite Xb with T
        #pragma unroll
        for (int cg = 0; cg < 8; ++cg)
            #pragma unroll
            for (int r = 0; r < 4; r++)
                Xb[(16 * w + 4 * lq + r) * 132 + 16 * cg + l16] = f2bf(tacc[cg][r]);
        __syncthreads();

        // ---- score assembly + online softmax ----
        float pvv[4][4];
        float tmax[4];
        #pragma unroll
        for (int r = 0; r < 4; r++) tmax[r] = -1e30f;
        const int mixed = (c0 == q0);
        #pragma unroll
        for (int fc = 0; fc < 4; ++fc) {
            int ci = 16 * fc + l16;
            #pragma unroll
            for (int r = 0; r < 4; r++) {
                int qi = 16 * w + 4 * lq + r;
                int t = ci - qi + 63;
                int sx = mixed ? ((ci >= qi + 1) ? 1 : 0) : 0;  // rowoff folded for pure tiles
                float tv = bf2f(Xb[(qi + sx) * 132 + t]);
                float sc = (cacc[fc][r] + tv) * 0.03125f;
                pvv[fc][r] = sc;
                tmax[r] = fmaxf(tmax[r], sc);
            }
        }
        #pragma unroll
        for (int d = 1; d < 16; d <<= 1)
            #pragma unroll
            for (int r = 0; r < 4; r++) tmax[r] = fmaxf(tmax[r], __shfl_xor(tmax[r], d, 64));

        float alpha[4], rsum[4];
        #pragma unroll
        for (int r = 0; r < 4; r++) {
            float nm = fmaxf(mrow[r], tmax[r]);
            alpha[r] = __expf(mrow[r] - nm);
            mrow[r] = nm;
            rsum[r] = 0.f;
        }
        #pragma unroll
        for (int fc = 0; fc < 4; ++fc)
            #pragma unroll
            for (int r = 0; r < 4; r++) {
                float p = __expf(pvv[fc][r] - mrow[r]);
                pvv[fc][r] = p;
                rsum[r] += p;
            }
        #pragma unroll
        for (int d = 1; d < 16; d <<= 1)
            #pragma unroll
            for (int r = 0; r < 4; r++) rsum[r] += __shfl_xor(rsum[r], d, 64);
        #pragma unroll
        for (int r = 0; r < 4; r++) lrow[r] = lrow[r] * alpha[r] + rsum[r];
        #pragma unroll
        for (int f = 0; f < 4; f++)
            #pragma unroll
            for (int r = 0; r < 4; r++) oacc[f][r] *= alpha[r];

        __syncthreads();   // all T reads complete -> overwrite Xb with Pattn
        #pragma unroll
        for (int fc = 0; fc < 4; ++fc)
            #pragma unroll
            for (int r = 0; r < 4; r++)
                Xb[(16 * w + 4 * lq + r) * 72 + 16 * fc + l16] = f2bf(pvv[fc][r]);
        __syncthreads();

        // ---- PV ----
        #pragma unroll
        for (int kk = 0; kk < 2; ++kk) {
            bf16x8 a = *(const bf16x8*)&Xb[(16 * w + l16) * 72 + kk * 32 + 8 * lq];
            #pragma unroll
            for (int fc = 0; fc < 4; ++fc) {
                bf16x8 b = *(const bf16x8*)&Vt[(16 * fc + l16) * 72 + kk * 32 + 8 * lq];
                oacc[fc] = __builtin_amdgcn_mfma_f32_16x16x32_bf16(a, b, oacc[fc], 0, 0, 0);
            }
        }
    }

    // epilogue: ctx[b, s, h, dh]
    const int b = bh >> 4, h = bh & 15;
    #pragma unroll
    for (int fc = 0; fc < 4; ++fc) {
        int dh = 16 * fc + l16;
        #pragma unroll
        for (int r = 0; r < 4; r++) {
            int qi = 16 * w + 4 * lq + r;
            int gq = q0 + qi;
            float val = oacc[fc][r] / lrow[r];
            CTX[(long)((b * S_LEN + gq) * NHEADS + h) * DHEAD + dh] = f2bf(val);
        }
    }
}

// ---------------------------------------------------------------------------
// Kernel 3: output GEMM.  out = ctx(bf16) @ Wo^T + bo, fp32 out.
// ---------------------------------------------------------------------------
__global__ __launch_bounds__(256) void out_gemm(
    const unsigned short* __restrict__ A,  // ctx bf16 [4096][1024]
    const float* __restrict__ W,           // Wo [1024][1024]
    const float* __restrict__ Bv,          // bo
    float* __restrict__ O)                 // [4096][1024] fp32
{
    __shared__ __align__(16) unsigned short At[128 * 40];
    __shared__ __align__(16) unsigned short Bt[128 * 40];

    const int tid  = threadIdx.x;
    const int lane = tid & 63;
    const int w    = tid >> 6;
    const int wr   = w & 1, wc = w >> 1;
    const int m0   = blockIdx.x * 128;
    const int n0   = blockIdx.y * 128;
    const int l16  = lane & 15, lq = lane >> 4;

    f32x4 acc[4][4];
    #pragma unroll
    for (int i = 0; i < 4; i++)
        #pragma unroll
        for (int j = 0; j < 4; j++) acc[i][j] = (f32x4){0.f, 0.f, 0.f, 0.f};

    for (int k0 = 0; k0 < DMODEL; k0 += 32) {
        __syncthreads();
        #pragma unroll
        for (int i = 0; i < 2; i++) {
            int e = tid + i * 256;
            int row = e >> 2, sg = e & 3;
            *(float4*)&At[row * 40 + sg * 8] =
                *(const float4*)&A[(long)(m0 + row) * DMODEL + k0 + sg * 8];
        }
        #pragma unroll
        for (int i = 0; i < 4; i++) {
            int e = tid + i * 256;
            int row = e >> 3, cg = e & 7;
            float4 vb = *(const float4*)&W[(long)(n0 + row) * DMODEL + k0 + cg * 4];
            ushort4 ub; ub.x = f2bf(vb.x); ub.y = f2bf(vb.y); ub.z = f2bf(vb.z); ub.w = f2bf(vb.w);
            *(ushort4*)&Bt[row * 40 + cg * 4] = ub;
        }
        __syncthreads();
        bf16x8 af[4], bfr[4];
        #pragma unroll
        for (int f = 0; f < 4; f++) {
            af[f]  = *(const bf16x8*)&At[(64 * wr + 16 * f + l16) * 40 + 8 * lq];
            bfr[f] = *(const bf16x8*)&Bt[(64 * wc + 16 * f + l16) * 40 + 8 * lq];
        }
        #pragma unroll
        for (int i = 0; i < 4; i++)
            #pragma unroll
            for (int j = 0; j < 4; j++)
                acc[i][j] = __builtin_amdgcn_mfma_f32_16x16x32_bf16(af[i], bfr[j], acc[i][j], 0, 0, 0);
    }

    #pragma unroll
    for (int j = 0; j < 4; j++) {
        int n_g = n0 + 64 * wc + 16 * j + l16;
        float bias = Bv[n_g];
        #pragma unroll
        for (int i = 0; i < 4; i++) {
            #pragma unroll
            for (int r = 0; r < 4; r++) {
                int m_g = m0 + 64 * wr + 16 * i + 4 * lq + r;
                O[(long)m_g * DMODEL + n_g] = acc[i][j][r] + bias;
            }
        }
    }
}

// ---------------------------------------------------------------------------
extern "C" void kernel_launch(void* const* d_in, const int* in_sizes, int n_in,
                              void* d_out, int out_size, void* d_ws, size_t ws_size,
                              hipStream_t stream) {
    (void)in_sizes; (void)n_in; (void)out_size; (void)ws_size;
    const float* query = (const float*)d_in[0];
    const float* key_  = (const float*)d_in[1];
    const float* value = (const float*)d_in[2];
    const float* pos   = (const float*)d_in[3];
    const float* Wq = (const float*)d_in[4];  const float* bq = (const float*)d_in[5];
    const float* Wk = (const float*)d_in[6];  const float* bk = (const float*)d_in[7];
    const float* Wv = (const float*)d_in[8];  const float* bv = (const float*)d_in[9];
    const float* Wp = (const float*)d_in[10]; const float* bp = (const float*)d_in[11];
    const float* Wo = (const float*)d_in[12]; const float* bo = (const float*)d_in[13];
    float* out = (float*)d_out;

    const long NE = (long)TOKENS * DMODEL;   // 4,194,304 elements per tensor
    unsigned short* qb = (unsigned short*)d_ws;
    unsigned short* kb = qb + NE;
    unsigned short* vb = kb + NE;
    unsigned short* pb = vb + NE;
    unsigned short* cx = pb + NE;            // total ws use: 5 * 8 MB = 40 MB

    proj_gemm<<<dim3(32, 8, 4), 256, 0, stream>>>(
        query, key_, value, pos, Wq, Wk, Wv, Wp, bq, bk, bv, bp, qb, kb, vb, pb);
    rel_attn<<<dim3(32, 32), 256, 0, stream>>>(qb, kb, vb, pb, cx);
    out_gemm<<<dim3(32, 8), 256, 0, stream>>>(cx, Wo, bo, out);
}

// Round 2
// 363.912 us; speedup vs baseline: 1.1376x; 1.1376x over previous
//
#include <hip/hip_runtime.h>
#include <hip/hip_bf16.h>

// Problem constants (fixed by harness setup_inputs).
#define S_LEN  2048
#define DMODEL 1024
#define NHEADS 16
#define DHEAD  64
#define TOKENS 4096   // B*S
#define QSCALE 0.04508422f   // (1/32) * log2(e): scores come out in log2 domain

typedef __attribute__((ext_vector_type(8))) short bf16x8;
typedef __attribute__((ext_vector_type(4))) float f32x4;

__device__ __forceinline__ unsigned short f2bf(float x) {
    union { float f; unsigned u; } v; v.f = x;
    unsigned r = v.u + 0x7FFFu + ((v.u >> 16) & 1u);   // RNE
    return (unsigned short)(r >> 16);
}
__device__ __forceinline__ float bf2f(unsigned short b) {
    union { unsigned u; float f; } v; v.u = ((unsigned)b) << 16;
    return v.f;
}
__device__ __forceinline__ unsigned cvt_pk_bf16(float lo, float hi) {
    unsigned r;
    asm("v_cvt_pk_bf16_f32 %0, %1, %2" : "=v"(r) : "v"(lo), "v"(hi));
    return r;
}

// ---------------------------------------------------------------------------
// Kernel 1: fused 4-way projection GEMM.  out = X @ W^T + b  (bf16).
// z=0 (q): scaled by QSCALE, layout [BH][S][64]
// z=1 (k), z=3 (p): layout [BH][S][64]
// z=2 (v): layout [BH][64][S]  (transposed, packed b64 stores)
// ---------------------------------------------------------------------------
__global__ __launch_bounds__(256) void proj_gemm(
    const float* __restrict__ x0, const float* __restrict__ x1,
    const float* __restrict__ x2, const float* __restrict__ x3,
    const float* __restrict__ w0, const float* __restrict__ w1,
    const float* __restrict__ w2, const float* __restrict__ w3,
    const float* __restrict__ b0, const float* __restrict__ b1,
    const float* __restrict__ b2, const float* __restrict__ b3,
    unsigned short* __restrict__ o0, unsigned short* __restrict__ o1,
    unsigned short* __restrict__ o2, unsigned short* __restrict__ o3)
{
    const int z = blockIdx.z;
    const float* X  = (z == 0) ? x0 : (z == 1) ? x1 : (z == 2) ? x2 : x3;
    const float* W  = (z == 0) ? w0 : (z == 1) ? w1 : (z == 2) ? w2 : w3;
    const float* Bv = (z == 0) ? b0 : (z == 1) ? b1 : (z == 2) ? b2 : b3;
    unsigned short* O = (z == 0) ? o0 : (z == 1) ? o1 : (z == 2) ? o2 : o3;

    __shared__ __align__(16) unsigned short At[128 * 40];
    __shared__ __align__(16) unsigned short Bt[128 * 40];

    const int tid  = threadIdx.x;
    const int lane = tid & 63;
    const int w    = tid >> 6;
    const int wr   = w & 1, wc = w >> 1;
    const int m0   = blockIdx.x * 128;
    const int n0   = blockIdx.y * 128;
    const int l16  = lane & 15, lq = lane >> 4;

    f32x4 acc[4][4];
    #pragma unroll
    for (int i = 0; i < 4; i++)
        #pragma unroll
        for (int j = 0; j < 4; j++) acc[i][j] = (f32x4){0.f, 0.f, 0.f, 0.f};

    for (int k0 = 0; k0 < DMODEL; k0 += 32) {
        __syncthreads();
        #pragma unroll
        for (int i = 0; i < 4; i++) {
            int e = tid + i * 256;
            int row = e >> 3, cg = e & 7;
            float4 va = *(const float4*)&X[(long)(m0 + row) * DMODEL + k0 + cg * 4];
            ushort4 ua; ua.x = f2bf(va.x); ua.y = f2bf(va.y); ua.z = f2bf(va.z); ua.w = f2bf(va.w);
            *(ushort4*)&At[row * 40 + cg * 4] = ua;
            float4 vb = *(const float4*)&W[(long)(n0 + row) * DMODEL + k0 + cg * 4];
            ushort4 ub; ub.x = f2bf(vb.x); ub.y = f2bf(vb.y); ub.z = f2bf(vb.z); ub.w = f2bf(vb.w);
            *(ushort4*)&Bt[row * 40 + cg * 4] = ub;
        }
        __syncthreads();
        bf16x8 af[4], bfr[4];
        #pragma unroll
        for (int f = 0; f < 4; f++) {
            af[f]  = *(const bf16x8*)&At[(64 * wr + 16 * f + l16) * 40 + 8 * lq];
            bfr[f] = *(const bf16x8*)&Bt[(64 * wc + 16 * f + l16) * 40 + 8 * lq];
        }
        #pragma unroll
        for (int i = 0; i < 4; i++)
            #pragma unroll
            for (int j = 0; j < 4; j++)
                acc[i][j] = __builtin_amdgcn_mfma_f32_16x16x32_bf16(af[i], bfr[j], acc[i][j], 0, 0, 0);
    }

    #pragma unroll
    for (int j = 0; j < 4; j++) {
        int n_g = n0 + 64 * wc + 16 * j + l16;
        float bias = Bv[n_g];
        int h = n_g >> 6, dh = n_g & 63;
        if (z == 2) {
            // V^T layout [BH][64][S]: 4 consecutive m (=s) -> packed 8B store
            #pragma unroll
            for (int i = 0; i < 4; i++) {
                int m_g = m0 + 64 * wr + 16 * i + 4 * lq;
                int b = m_g >> 11, s = m_g & (S_LEN - 1);
                ushort4 u;
                u.x = f2bf(acc[i][j][0] + bias);
                u.y = f2bf(acc[i][j][1] + bias);
                u.z = f2bf(acc[i][j][2] + bias);
                u.w = f2bf(acc[i][j][3] + bias);
                *(ushort4*)&O[(long)(((b * NHEADS + h) * DHEAD) + dh) * S_LEN + s] = u;
            }
        } else {
            float scale = (z == 0) ? QSCALE : 1.0f;
            #pragma unroll
            for (int i = 0; i < 4; i++) {
                #pragma unroll
                for (int r = 0; r < 4; r++) {
                    int m_g = m0 + 64 * wr + 16 * i + 4 * lq + r;
                    int b = m_g >> 11, s = m_g & (S_LEN - 1);
                    O[(long)(((b * NHEADS + h) * S_LEN) + s) * DHEAD + dh] =
                        f2bf((acc[i][j][r] + bias) * scale);
                }
            }
        }
    }
}

// ---------------------------------------------------------------------------
// Kernel 2: fused relative-position flash attention (swapped-score structure).
// Grid: (q-tile 0..31, bh 0..31). 4 waves; wave w owns q-rows 16w..16w+15.
// Swapped MFMA: lane&15 = q-row; regs = ci (content) / t' (pos) / dh (out).
// Pos score: T_w[r][t'] = q[q0+16w+ro+r] . P2[Mw+t'], Mw = mbase'-16w-15,
// read at row l16 (pure tiles, ro=c0>q0 baked in) / per-element for mixed.
// ---------------------------------------------------------------------------
__global__ __launch_bounds__(256) void rel_attn(
    const unsigned short* __restrict__ Q,   // [BH][S][64] bf16, pre-scaled
    const unsigned short* __restrict__ K,   // [BH][S][64]
    const unsigned short* __restrict__ VT,  // [BH][64][S]
    const unsigned short* __restrict__ P,   // [BH][S][64]
    unsigned short* __restrict__ CTX)       // [B][S][H][64] bf16
{
    __shared__ __align__(16) unsigned short Kt[64 * 72];
    __shared__ __align__(16) unsigned short Vt[64 * 72];       // [dh][ci] (from VT)
    __shared__ __align__(16) unsigned short P2w[128 * 72];
    __shared__ __align__(16) unsigned short Tb[4 * 16 * 84];   // [w][qrow][t']

    const int tid  = threadIdx.x;
    const int lane = tid & 63;
    const int w    = tid >> 6;
    const int l16  = lane & 15;
    const int lq   = lane >> 4;
    const int q0   = blockIdx.x * 64;
    const int bh   = blockIdx.y;
    const long base = (long)bh * S_LEN * DHEAD;
    const int qi_l = 16 * w + l16;

    const int r8 = tid >> 3, sg8 = tid & 7;

    // ds_bpermute source-lane byte addresses: src = ((t&16)<<1)|(c<<4)|(t&15)
    const int bpa0 = ((((lane & 16) << 1) | (lane & 15)) << 2);
    const int bpa1 = bpa0 + 64;
    const bool hiw = (lane & 32) != 0;

    // hoisted Q fragments: rows qi_l (+0) and qi_l+1
    bf16x8 qf0[2], qf1[2];
    {
        const unsigned short* qrow = Q + base + (long)(q0 + qi_l) * DHEAD + 8 * lq;
        #pragma unroll
        for (int kk = 0; kk < 2; kk++) {
            qf0[kk] = *(const bf16x8*)(qrow + 32 * kk);
            qf1[kk] = *(const bf16x8*)(qrow + DHEAD + 32 * kk);
        }
    }

    float mrow = -1e30f, lrow = 0.f;
    f32x4 oacc[4];
    #pragma unroll
    for (int f = 0; f < 4; f++) oacc[f] = (f32x4){0.f, 0.f, 0.f, 0.f};

    for (int ct = 0; ct < S_LEN / 64; ++ct) {
        const int c0 = ct * 64;
        const int W0 = c0 - q0 + 1984;   // lowest P2 index needed

        __syncthreads();   // previous tile's reads complete

        // ---- stage K rows and V^T rows (both vectorized b128) ----
        #pragma unroll
        for (int i = 0; i < 2; i++) {
            int row = r8 + 32 * i;
            *(float4*)&Kt[row * 72 + sg8 * 8] =
                *(const float4*)&K[base + (long)(c0 + row) * DHEAD + sg8 * 8];
            *(float4*)&Vt[row * 72 + sg8 * 8] =
                *(const float4*)&VT[base + (long)row * S_LEN + c0 + sg8 * 8];
        }
        // ---- stage P2 window (128 rows; m==2048 is the zero row) ----
        #pragma unroll
        for (int i = 0; i < 4; i++) {
            int row = r8 + 32 * i;
            int m = W0 + row;
            int pr = (m >= 2049) ? (m - 2049) : m;
            float4 val = *(const float4*)&P[base + (long)pr * DHEAD + sg8 * 8];
            if (m == 2048) val = (float4){0.f, 0.f, 0.f, 0.f};
            *(float4*)&P2w[row * 72 + sg8 * 8] = val;
        }
        __syncthreads();

        // ---- content scores (swapped): cacc[fc][r] = S[ci=16fc+4lq+r][qi_l]
        f32x4 cacc[4];
        #pragma unroll
        for (int f = 0; f < 4; f++) cacc[f] = (f32x4){0.f, 0.f, 0.f, 0.f};
        #pragma unroll
        for (int fc = 0; fc < 4; ++fc)
            #pragma unroll
            for (int kk = 0; kk < 2; ++kk) {
                bf16x8 kf = *(const bf16x8*)&Kt[(16 * fc + l16) * 72 + 32 * kk + 8 * lq];
                cacc[fc] = __builtin_amdgcn_mfma_f32_16x16x32_bf16(kf, qf0[kk], cacc[fc], 0, 0, 0);
            }

        // ---- pos tile: per-wave 80-wide window, rows shifted by ro ----
        const int su = (c0 > q0) ? 1 : 0;
        const int woff = 48 - 16 * w;
        f32x4 tacc[5];
        #pragma unroll
        for (int g = 0; g < 5; g++) tacc[g] = (f32x4){0.f, 0.f, 0.f, 0.f};
        #pragma unroll
        for (int cg = 0; cg < 5; ++cg)
            #pragma unroll
            for (int kk = 0; kk < 2; ++kk) {
                bf16x8 pf = *(const bf16x8*)&P2w[(woff + 16 * cg + l16) * 72 + 32 * kk + 8 * lq];
                bf16x8 qa = su ? qf1[kk] : qf0[kk];
                tacc[cg] = __builtin_amdgcn_mfma_f32_16x16x32_bf16(pf, qa, tacc[cg], 0, 0, 0);
            }
        // packed T writeback: lane's 4 t'-consecutive values -> one b64
        {
            unsigned short* tw = &Tb[w * 1344 + l16 * 84 + 4 * lq];
            #pragma unroll
            for (int cg = 0; cg < 5; ++cg) {
                uint2 u;
                u.x = cvt_pk_bf16(tacc[cg][0], tacc[cg][1]);
                u.y = cvt_pk_bf16(tacc[cg][2], tacc[cg][3]);
                *(uint2*)(tw + 16 * cg) = u;
            }
        }
        __syncthreads();

        // ---- score assembly ----
        float sc[4][4];
        if (c0 != q0) {
            const unsigned short* tp = &Tb[w * 1344 + l16 * 83 + 15 + 4 * lq];
            #pragma unroll
            for (int fc = 0; fc < 4; ++fc)
                #pragma unroll
                for (int r = 0; r < 4; ++r)
                    sc[fc][r] = cacc[fc][r] + bf2f(tp[16 * fc + r]);
        } else {
            #pragma unroll
            for (int fc = 0; fc < 4; ++fc)
                #pragma unroll
                for (int r = 0; r < 4; ++r) {
                    int ci = 16 * fc + 4 * lq + r;
                    int sx = (ci > qi_l) ? 1 : 0;
                    int rg = l16 + sx;
                    int adr = (w + (rg >> 4)) * 1344 + (rg & 15) * 84
                            + ci - l16 + 15 + ((rg >> 4) << 4);
                    sc[fc][r] = cacc[fc][r] + bf2f(Tb[adr]);
                }
        }

        // ---- online softmax (log2 domain; per-lane row qi_l) ----
        float tmax = sc[0][0];
        #pragma unroll
        for (int fc = 0; fc < 4; ++fc)
            #pragma unroll
            for (int r = 0; r < 4; ++r) tmax = fmaxf(tmax, sc[fc][r]);
        tmax = fmaxf(tmax, __shfl_xor(tmax, 16, 64));
        tmax = fmaxf(tmax, __shfl_xor(tmax, 32, 64));
        float nm = fmaxf(mrow, tmax);
        float alpha = exp2f(mrow - nm);
        mrow = nm;
        float pv[4][4];
        float rs = 0.f;
        #pragma unroll
        for (int fc = 0; fc < 4; ++fc)
            #pragma unroll
            for (int r = 0; r < 4; ++r) {
                float p = exp2f(sc[fc][r] - nm);
                pv[fc][r] = p;
                rs += p;
            }
        rs += __shfl_xor(rs, 16, 64);
        rs += __shfl_xor(rs, 32, 64);
        lrow = lrow * alpha + rs;
        #pragma unroll
        for (int f = 0; f < 4; f++)
            #pragma unroll
            for (int r = 0; r < 4; r++) oacc[f][r] *= alpha;

        // ---- pack P -> bf16 pairs, redistribute across lq via bpermute ----
        unsigned p32[4][2];
        #pragma unroll
        for (int fc = 0; fc < 4; ++fc) {
            p32[fc][0] = cvt_pk_bf16(pv[fc][0], pv[fc][1]);
            p32[fc][1] = cvt_pk_bf16(pv[fc][2], pv[fc][3]);
        }
        bf16x8 pfr[2];
        #pragma unroll
        for (int kk = 0; kk < 2; ++kk) {
            union { unsigned u[4]; bf16x8 v; } pu;
            #pragma unroll
            for (int j2 = 0; j2 < 4; ++j2) {
                int rp = j2 & 1;
                int ba = (j2 & 2) ? bpa1 : bpa0;
                unsigned g0 = (unsigned)__builtin_amdgcn_ds_bpermute(ba, (int)p32[2 * kk][rp]);
                unsigned g1 = (unsigned)__builtin_amdgcn_ds_bpermute(ba, (int)p32[2 * kk + 1][rp]);
                pu.u[j2] = hiw ? g1 : g0;
            }
            pfr[kk] = pu.v;
        }

        // ---- PV: O^acc[fa][r] = O[qi_l][dh=16fa+4lq+r] ----
        #pragma unroll
        for (int kk = 0; kk < 2; ++kk)
            #pragma unroll
            for (int fa = 0; fa < 4; ++fa) {
                bf16x8 vf = *(const bf16x8*)&Vt[(16 * fa + l16) * 72 + 32 * kk + 8 * lq];
                oacc[fa] = __builtin_amdgcn_mfma_f32_16x16x32_bf16(vf, pfr[kk], oacc[fa], 0, 0, 0);
            }
    }

    // epilogue: lane owns row q0+qi_l; 4 consecutive dh -> packed 8B stores
    const int b = bh >> 4, h = bh & 15;
    const float rinv = 1.0f / lrow;
    unsigned short* op = CTX + ((long)(b * S_LEN + q0 + qi_l) * NHEADS + h) * DHEAD + 4 * lq;
    #pragma unroll
    for (int fa = 0; fa < 4; ++fa) {
        ushort4 u;
        u.x = f2bf(oacc[fa][0] * rinv);
        u.y = f2bf(oacc[fa][1] * rinv);
        u.z = f2bf(oacc[fa][2] * rinv);
        u.w = f2bf(oacc[fa][3] * rinv);
        *(ushort4*)(op + 16 * fa) = u;
    }
}

// ---------------------------------------------------------------------------
// Kernel 3: output GEMM.  out = ctx(bf16) @ Wo^T + bo, fp32 out.
// ---------------------------------------------------------------------------
__global__ __launch_bounds__(256) void out_gemm(
    const unsigned short* __restrict__ A,  // ctx bf16 [4096][1024]
    const float* __restrict__ W,           // Wo [1024][1024]
    const float* __restrict__ Bv,          // bo
    float* __restrict__ O)                 // [4096][1024] fp32
{
    __shared__ __align__(16) unsigned short At[128 * 40];
    __shared__ __align__(16) unsigned short Bt[128 * 40];

    const int tid  = threadIdx.x;
    const int lane = tid & 63;
    const int w    = tid >> 6;
    const int wr   = w & 1, wc = w >> 1;
    const int m0   = blockIdx.x * 128;
    const int n0   = blockIdx.y * 128;
    const int l16  = lane & 15, lq = lane >> 4;

    f32x4 acc[4][4];
    #pragma unroll
    for (int i = 0; i < 4; i++)
        #pragma unroll
        for (int j = 0; j < 4; j++) acc[i][j] = (f32x4){0.f, 0.f, 0.f, 0.f};

    for (int k0 = 0; k0 < DMODEL; k0 += 32) {
        __syncthreads();
        #pragma unroll
        for (int i = 0; i < 2; i++) {
            int e = tid + i * 256;
            int row = e >> 2, sg = e & 3;
            *(float4*)&At[row * 40 + sg * 8] =
                *(const float4*)&A[(long)(m0 + row) * DMODEL + k0 + sg * 8];
        }
        #pragma unroll
        for (int i = 0; i < 4; i++) {
            int e = tid + i * 256;
            int row = e >> 3, cg = e & 7;
            float4 vb = *(const float4*)&W[(long)(n0 + row) * DMODEL + k0 + cg * 4];
            ushort4 ub; ub.x = f2bf(vb.x); ub.y = f2bf(vb.y); ub.z = f2bf(vb.z); ub.w = f2bf(vb.w);
            *(ushort4*)&Bt[row * 40 + cg * 4] = ub;
        }
        __syncthreads();
        bf16x8 af[4], bfr[4];
        #pragma unroll
        for (int f = 0; f < 4; f++) {
            af[f]  = *(const bf16x8*)&At[(64 * wr + 16 * f + l16) * 40 + 8 * lq];
            bfr[f] = *(const bf16x8*)&Bt[(64 * wc + 16 * f + l16) * 40 + 8 * lq];
        }
        #pragma unroll
        for (int i = 0; i < 4; i++)
            #pragma unroll
            for (int j = 0; j < 4; j++)
                acc[i][j] = __builtin_amdgcn_mfma_f32_16x16x32_bf16(af[i], bfr[j], acc[i][j], 0, 0, 0);
    }

    #pragma unroll
    for (int j = 0; j < 4; j++) {
        int n_g = n0 + 64 * wc + 16 * j + l16;
        float bias = Bv[n_g];
        #pragma unroll
        for (int i = 0; i < 4; i++) {
            #pragma unroll
            for (int r = 0; r < 4; r++) {
                int m_g = m0 + 64 * wr + 16 * i + 4 * lq + r;
                O[(long)m_g * DMODEL + n_g] = acc[i][j][r] + bias;
            }
        }
    }
}

// ---------------------------------------------------------------------------
extern "C" void kernel_launch(void* const* d_in, const int* in_sizes, int n_in,
                              void* d_out, int out_size, void* d_ws, size_t ws_size,
                              hipStream_t stream) {
    (void)in_sizes; (void)n_in; (void)out_size; (void)ws_size;
    const float* query = (const float*)d_in[0];
    const float* key_  = (const float*)d_in[1];
    const float* value = (const float*)d_in[2];
    const float* pos   = (const float*)d_in[3];
    const float* Wq = (const float*)d_in[4];  const float* bq = (const float*)d_in[5];
    const float* Wk = (const float*)d_in[6];  const float* bk = (const float*)d_in[7];
    const float* Wv = (const float*)d_in[8];  const float* bv = (const float*)d_in[9];
    const float* Wp = (const float*)d_in[10]; const float* bp = (const float*)d_in[11];
    const float* Wo = (const float*)d_in[12]; const float* bo = (const float*)d_in[13];
    float* out = (float*)d_out;

    const long NE = (long)TOKENS * DMODEL;   // 4,194,304 elements per tensor
    unsigned short* qb = (unsigned short*)d_ws;
    unsigned short* kb = qb + NE;
    unsigned short* vb = kb + NE;            // V^T layout [BH][64][S]
    unsigned short* pb = vb + NE;
    unsigned short* cx = pb + NE;            // total ws use: 5 * 8 MB = 40 MB

    proj_gemm<<<dim3(32, 8, 4), 256, 0, stream>>>(
        query, key_, value, pos, Wq, Wk, Wv, Wp, bq, bk, bv, bp, qb, kb, vb, pb);
    rel_attn<<<dim3(32, 32), 256, 0, stream>>>(qb, kb, vb, pb, cx);
    out_gemm<<<dim3(32, 8), 256, 0, stream>>>(cx, Wo, bo, out);
}